// Round 2
// baseline (14851.041 us; speedup 1.0000x reference)
//
#include <hip/hip_runtime.h>

#define B_ 64
#define S_ 512
#define I_ 512
#define H_ 512

typedef unsigned short u16;
typedef unsigned int   u32;

typedef __attribute__((ext_vector_type(8))) short   bf16x8;
typedef __attribute__((ext_vector_type(4))) float   f32x4;
typedef __attribute__((ext_vector_type(2))) _Float16 h2_t;

// ---------- helpers ----------
__device__ inline u16 f2bf(float f) {            // RNE fp32 -> bf16 bits
  u32 u = __builtin_bit_cast(u32, f);
  u32 r = (u + 0x7fffu + ((u >> 16) & 1u)) >> 16;
  return (u16)r;
}
__device__ inline u32 pk2h(float a, float b) {   // pack two f32 -> half2 bits
  _Float16 x = (_Float16)a, y = (_Float16)b;
  return (u32)__builtin_bit_cast(u16, x) | ((u32)__builtin_bit_cast(u16, y) << 16);
}
__device__ inline float dot2(u32 w, u32 h, float acc) {
#if __has_builtin(__builtin_amdgcn_fdot2)
  return __builtin_amdgcn_fdot2(__builtin_bit_cast(h2_t, w),
                                __builtin_bit_cast(h2_t, h), acc, false);
#else
  h2_t a = __builtin_bit_cast(h2_t, w), b = __builtin_bit_cast(h2_t, h);
  return acc + (float)a[0] * (float)b[0] + (float)a[1] * (float)b[1];
#endif
}
__device__ inline float sigmoidf_(float x) { return 1.f / (1.f + __expf(-x)); }
__device__ inline float tanhf_(float x) {
  float e = __expf(-2.f * fabsf(x));
  float t = (1.f - e) / (1.f + e);
  return copysignf(t, x);
}

// ---------- kernel 1: x fp32 -> bf16 ----------
__global__ void k_convert_x(const float4* __restrict__ x, uint2* __restrict__ xb) {
  int i = blockIdx.x * 256 + threadIdx.x;   // covers B*S*I/4 = 4,194,304
  float4 v = x[i];
  uint2 o;
  o.x = (u32)f2bf(v.x) | ((u32)f2bf(v.y) << 16);
  o.y = (u32)f2bf(v.z) | ((u32)f2bf(v.w) << 16);
  xb[i] = o;
}

// ---------- kernel 2: split/convert W ----------
// Wxb[g][n][k] = bf16(W_g[n, k])   (k < 512, input half, for MFMA proj GEMM)
// W4[g][d2][m] = uint4 of half2 pairs for the recurrent half (cols 512..1023):
//   .x = (W[2m,   512+4d2],   W[2m,   512+4d2+1])
//   .y = (W[2m+1, 512+4d2],   W[2m+1, 512+4d2+1])
//   .z = (W[2m,   512+4d2+2], W[2m,   512+4d2+3])
//   .w = (W[2m+1, 512+4d2+2], W[2m+1, 512+4d2+3])
__global__ void k_convert_w(const float* __restrict__ Wr, const float* __restrict__ Wz,
                            const float* __restrict__ Wh,
                            u16* __restrict__ Wxb, uint4* __restrict__ W4) {
  int g = blockIdx.y;
  const float* Ws = (g == 0) ? Wr : ((g == 1) ? Wz : Wh);
  int idx = blockIdx.x * 256 + threadIdx.x;
  if (idx < 262144) {
    int n = idx >> 9, k = idx & 511;
    Wxb[g * 262144 + idx] = f2bf(Ws[(size_t)n * 1024 + k]);
  } else {
    int i  = idx - 262144;           // 0..32767
    int m  = i & 255, d2 = i >> 8;   // d2: 0..127
    const float* r0 = Ws + (size_t)(2 * m) * 1024 + 512 + 4 * d2;
    const float* r1 = Ws + (size_t)(2 * m + 1) * 1024 + 512 + 4 * d2;
    uint4 o;
    o.x = pk2h(r0[0], r0[1]);
    o.y = pk2h(r1[0], r1[1]);
    o.z = pk2h(r0[2], r0[3]);
    o.w = pk2h(r1[2], r1[3]);
    W4[(size_t)g * 32768 + (size_t)d2 * 256 + m] = o;
  }
}

// ---------- kernel 3: projection GEMM (bf16 MFMA) ----------
__global__ __launch_bounds__(256) void k_proj_gemm(
    const u16* __restrict__ Xb,      // [32768][512] bf16
    const u16* __restrict__ Wxb,     // [3][512][512] bf16
    const float* __restrict__ br, const float* __restrict__ bz, const float* __restrict__ bh,
    u16* __restrict__ P)             // [3][32768][512] f16
{
  const int g  = blockIdx.z;
  const int bm = blockIdx.x * 64;
  const int bn = blockIdx.y * 64;
  __shared__ u16 As[64][32];
  __shared__ u16 Bs[64][32];
  const int tid  = threadIdx.x;
  const int lane = tid & 63;
  const int wm   = (tid >> 6) >> 1;
  const int wn   = (tid >> 6) & 1;
  const int srow = tid >> 2;
  const int scol = (tid & 3) * 8;
  const u16* Wg = Wxb + (size_t)g * (512 * 512);

  f32x4 zero4 = {0.f, 0.f, 0.f, 0.f};
  f32x4 acc[2][2];
  acc[0][0] = zero4; acc[0][1] = zero4; acc[1][0] = zero4; acc[1][1] = zero4;

  for (int k0 = 0; k0 < 512; k0 += 32) {
    __syncthreads();
    *(int4*)(&As[srow][scol]) = *(const int4*)(Xb + (size_t)(bm + srow) * 512 + k0 + scol);
    *(int4*)(&Bs[srow][scol]) = *(const int4*)(Wg + (size_t)(bn + srow) * 512 + k0 + scol);
    __syncthreads();
#pragma unroll
    for (int mi = 0; mi < 2; ++mi) {
      bf16x8 a = *(const bf16x8*)(&As[wm * 32 + mi * 16 + (lane & 15)][(lane >> 4) * 8]);
#pragma unroll
      for (int ni = 0; ni < 2; ++ni) {
        bf16x8 b = *(const bf16x8*)(&Bs[wn * 32 + ni * 16 + (lane & 15)][(lane >> 4) * 8]);
        acc[mi][ni] = __builtin_amdgcn_mfma_f32_16x16x32_bf16(a, b, acc[mi][ni], 0, 0, 0);
      }
    }
  }
  const float* bias = (g == 0) ? br : ((g == 1) ? bz : bh);
  u16* Pg = P + (size_t)g * ((size_t)32768 * 512);
#pragma unroll
  for (int mi = 0; mi < 2; ++mi)
#pragma unroll
    for (int ni = 0; ni < 2; ++ni) {
      int col  = bn + wn * 32 + ni * 16 + (lane & 15);
      float bv = bias[col];
#pragma unroll
      for (int r = 0; r < 4; ++r) {
        int row = bm + wm * 32 + mi * 16 + (lane >> 4) * 4 + r;
        float v = acc[mi][ni][r] + bv;
        Pg[(size_t)row * 512 + col] = __builtin_bit_cast(u16, (_Float16)v);
      }
    }
}

// ---------- kernel 4: sequential GRU scan ----------
// 32 blocks x 1024 threads (16 waves). Block owns 2 batches for all 512 steps.
// Phase 1 (r,z): thread -> (gate g1 = t>>9, k-half kh = lane&1, out-pair m1),
//   64 iters of uint4 W load + 8 dot2; reduce across lane pairs via shfl_xor(1).
// Phase 2 (htilde): thread -> (k-quarter q2 = lane&3, out-pair m2),
//   32 iters; reduce via shfl_xor(1), shfl_xor(2).
// Only 2 __syncthreads per step.
__global__ __launch_bounds__(1024) void k_gru_scan(
    const float* __restrict__ h0,
    const u16*  __restrict__ P,       // [3][B*S][512] f16 bits
    const uint4* __restrict__ W4,     // [3][128][256] packed quads
    float* __restrict__ y,            // [B][S][512]
    float* __restrict__ hlast)        // [B][512]
{
  const int b0 = blockIdx.x * 2;
  const int t  = threadIdx.x;
  const int l  = t & 63;
  const size_t PJ = (size_t)B_ * S_ * H_;

  __shared__ uint4  hq[128];    // packed h:  [d2] = {b0 k(4d2,+1), b0 k(+2,+3), b1 .., b1 ..}
  __shared__ uint4  rhq[128];   // packed r*h, same layout
  __shared__ float4 zf4[256];   // z for outputs (2m,2m+1) x 2 batches
  __shared__ float4 hf[256];    // f32 h for outputs (2m,2m+1) x 2 batches
  u32* hqu  = (u32*)hq;
  u32* rhqu = (u32*)rhq;

  if (t < 256) {
    int m = t;
    float a = h0[(size_t)b0 * H_ + 2 * m];
    float b = h0[(size_t)b0 * H_ + 2 * m + 1];
    float c = h0[(size_t)(b0 + 1) * H_ + 2 * m];
    float d = h0[(size_t)(b0 + 1) * H_ + 2 * m + 1];
    float4 hv = {a, b, c, d};
    hf[m] = hv;
    hqu[(m >> 1) * 4 + (m & 1)]     = pk2h(a, b);
    hqu[(m >> 1) * 4 + 2 + (m & 1)] = pk2h(c, d);
  }
  __syncthreads();

  // phase-1 mapping
  const int g1  = t >> 9;
  const int wv1 = (t & 511) >> 6;
  const int m1  = wv1 * 32 + (l >> 1);
  const int kh  = l & 1;
  const uint4* W1  = W4 + (size_t)g1 * 32768 + (size_t)kh * 64 * 256 + m1;
  const u16*   P1a = P + (size_t)g1 * PJ + ((size_t)b0 * S_) * H_ + 2 * m1;
  const u16*   P1b = P + (size_t)g1 * PJ + ((size_t)(b0 + 1) * S_) * H_ + 2 * m1;

  // phase-2 mapping
  const int wv2 = t >> 6;
  const int m2  = wv2 * 16 + (l >> 2);
  const int q2  = l & 3;
  const uint4* W2  = W4 + (size_t)2 * 32768 + (size_t)q2 * 32 * 256 + m2;
  const u16*   P2a = P + (size_t)2 * PJ + ((size_t)b0 * S_) * H_ + 2 * m2;
  const u16*   P2b = P + (size_t)2 * PJ + ((size_t)(b0 + 1) * S_) * H_ + 2 * m2;

  for (int ts = 0; ts < S_; ++ts) {
    // ---- phase 1: r/z partial GEMV ----
    float a00 = 0.f, a01 = 0.f, a10 = 0.f, a11 = 0.f;
#pragma unroll 8
    for (int i = 0; i < 64; ++i) {
      uint4 w  = W1[(size_t)i * 256];
      uint4 h4 = hq[kh * 64 + i];
      a00 = dot2(w.x, h4.x, a00); a01 = dot2(w.y, h4.x, a01);
      a10 = dot2(w.x, h4.z, a10); a11 = dot2(w.y, h4.z, a11);
      a00 = dot2(w.z, h4.y, a00); a01 = dot2(w.w, h4.y, a01);
      a10 = dot2(w.z, h4.w, a10); a11 = dot2(w.w, h4.w, a11);
    }
    a00 += __shfl_xor(a00, 1); a01 += __shfl_xor(a01, 1);
    a10 += __shfl_xor(a10, 1); a11 += __shfl_xor(a11, 1);
    if (kh == 0) {
      h2_t q0 = __builtin_bit_cast(h2_t, *(const u32*)(P1a + (size_t)ts * H_));
      h2_t q1 = __builtin_bit_cast(h2_t, *(const u32*)(P1b + (size_t)ts * H_));
      float v00 = sigmoidf_(a00 + (float)q0[0]);
      float v01 = sigmoidf_(a01 + (float)q0[1]);
      float v10 = sigmoidf_(a10 + (float)q1[0]);
      float v11 = sigmoidf_(a11 + (float)q1[1]);
      if (g1 == 0) {
        float4 hv = hf[m1];
        rhqu[(m1 >> 1) * 4 + (m1 & 1)]     = pk2h(v00 * hv.x, v01 * hv.y);
        rhqu[(m1 >> 1) * 4 + 2 + (m1 & 1)] = pk2h(v10 * hv.z, v11 * hv.w);
      } else {
        float4 zv = {v00, v01, v10, v11};
        zf4[m1] = zv;
      }
    }
    __syncthreads();

    // ---- phase 2: htilde partial GEMV ----
    float c00 = 0.f, c01 = 0.f, c10 = 0.f, c11 = 0.f;
#pragma unroll 8
    for (int i = 0; i < 32; ++i) {
      uint4 w  = W2[(size_t)i * 256];
      uint4 r4 = rhq[q2 * 32 + i];
      c00 = dot2(w.x, r4.x, c00); c01 = dot2(w.y, r4.x, c01);
      c10 = dot2(w.x, r4.z, c10); c11 = dot2(w.y, r4.z, c11);
      c00 = dot2(w.z, r4.y, c00); c01 = dot2(w.w, r4.y, c01);
      c10 = dot2(w.z, r4.w, c10); c11 = dot2(w.w, r4.w, c11);
    }
    c00 += __shfl_xor(c00, 1); c01 += __shfl_xor(c01, 1);
    c10 += __shfl_xor(c10, 1); c11 += __shfl_xor(c11, 1);
    c00 += __shfl_xor(c00, 2); c01 += __shfl_xor(c01, 2);
    c10 += __shfl_xor(c10, 2); c11 += __shfl_xor(c11, 2);
    if (q2 == 0) {
      h2_t q0 = __builtin_bit_cast(h2_t, *(const u32*)(P2a + (size_t)ts * H_));
      h2_t q1 = __builtin_bit_cast(h2_t, *(const u32*)(P2b + (size_t)ts * H_));
      float4 hv = hf[m2];
      float4 zv = zf4[m2];
      float t00 = tanhf_(c00 + (float)q0[0]);
      float t01 = tanhf_(c01 + (float)q0[1]);
      float t10 = tanhf_(c10 + (float)q1[0]);
      float t11 = tanhf_(c11 + (float)q1[1]);
      float n00 = zv.x * t00 + (1.f - zv.x) * hv.x;
      float n01 = zv.y * t01 + (1.f - zv.y) * hv.y;
      float n10 = zv.z * t10 + (1.f - zv.z) * hv.z;
      float n11 = zv.w * t11 + (1.f - zv.w) * hv.w;
      float4 nh = {n00, n01, n10, n11};
      hf[m2] = nh;
      hqu[(m2 >> 1) * 4 + (m2 & 1)]     = pk2h(n00, n01);
      hqu[(m2 >> 1) * 4 + 2 + (m2 & 1)] = pk2h(n10, n11);
      float2 y0 = {n00, n01};
      float2 y1 = {n10, n11};
      *(float2*)(y + ((size_t)b0 * S_ + ts) * H_ + 2 * m2)       = y0;
      *(float2*)(y + ((size_t)(b0 + 1) * S_ + ts) * H_ + 2 * m2) = y1;
    }
    __syncthreads();
  }

  if (t < 256) {
    int m = t;
    float4 hv = hf[m];
    float2 h0v = {hv.x, hv.y}, h1v = {hv.z, hv.w};
    *(float2*)(hlast + (size_t)b0 * H_ + 2 * m)       = h0v;
    *(float2*)(hlast + (size_t)(b0 + 1) * H_ + 2 * m) = h1v;
  }
}

// ---------- host ----------
extern "C" void kernel_launch(void* const* d_in, const int* in_sizes, int n_in,
                              void* d_out, int out_size, void* d_ws, size_t ws_size,
                              hipStream_t stream) {
  const float* x  = (const float*)d_in[0];
  const float* h0 = (const float*)d_in[1];
  const float* Wr = (const float*)d_in[2];
  const float* br = (const float*)d_in[3];
  const float* Wz = (const float*)d_in[4];
  const float* bz = (const float*)d_in[5];
  const float* Wh = (const float*)d_in[6];
  const float* bh = (const float*)d_in[7];

  char* ws = (char*)d_ws;
  // layout: Xb 32MB | Wxb 1.5MB | W4 1.5MB | P 96MB  (total ~131MB)
  u16*   Xb  = (u16*)ws;
  u16*   Wxb = (u16*)(ws + 33554432);
  uint4* W4  = (uint4*)(ws + 35127296);
  u16*   P   = (u16*)(ws + 36700160);

  float* y     = (float*)d_out;
  float* hlast = y + (size_t)B_ * S_ * H_;

  k_convert_x<<<dim3(16384), dim3(256), 0, stream>>>((const float4*)x, (uint2*)Xb);
  k_convert_w<<<dim3(1152, 3), dim3(256), 0, stream>>>(Wr, Wz, Wh, Wxb, W4);
  k_proj_gemm<<<dim3(512, 8, 3), dim3(256), 0, stream>>>(Xb, Wxb, br, bz, bh, P);
  k_gru_scan<<<dim3(32), dim3(1024), 0, stream>>>(h0, P, W4, y, hlast);
}

// Round 3
// 3263.715 us; speedup vs baseline: 4.5503x; 4.5503x over previous
//
#include <hip/hip_runtime.h>

#define B_ 64
#define S_ 512
#define H_ 512

typedef unsigned short u16;
typedef unsigned int   u32;

typedef __attribute__((ext_vector_type(8))) short    bf16x8;
typedef __attribute__((ext_vector_type(8))) _Float16 f16x8;
typedef __attribute__((ext_vector_type(4))) float    f32x4;
typedef __attribute__((ext_vector_type(2))) _Float16 h2_t;

#define PJ_GATE ((size_t)512 * 64 * 512)   // P stride per gate: [512 ts][64 b][512 j]

// ---------- helpers ----------
__device__ inline u16 f2bf(float f) {            // RNE fp32 -> bf16 bits
  u32 u = __builtin_bit_cast(u32, f);
  u32 r = (u + 0x7fffu + ((u >> 16) & 1u)) >> 16;
  return (u16)r;
}
__device__ inline u32 pkbf2(float a, float b) {
  return (u32)f2bf(a) | ((u32)f2bf(b) << 16);
}
__device__ inline u32 pk2h(float a, float b) {   // pack two f32 -> half2 bits
  _Float16 x = (_Float16)a, y = (_Float16)b;
  return (u32)__builtin_bit_cast(u16, x) | ((u32)__builtin_bit_cast(u16, y) << 16);
}
__device__ inline float sigmoidf_(float x) { return 1.f / (1.f + __expf(-x)); }
__device__ inline float tanhf_(float x) {
  float e = __expf(-2.f * fabsf(x));
  float t = (1.f - e) / (1.f + e);
  return copysignf(t, x);
}

// ---------- kernel 1: W recurrent half -> f16 MFMA A-fragments ----------
// WF[g][rt][kt][lane] (uint4) : 8 f16 = W_g[rt*16 + (lane&15)][512 + kt*32 + (lane>>4)*8 + 0..7]
__global__ void k_convert_w(const float* __restrict__ Wr, const float* __restrict__ Wz,
                            const float* __restrict__ Wh, uint4* __restrict__ WF) {
  int g = blockIdx.y;
  const float* Ws = (g == 0) ? Wr : ((g == 1) ? Wz : Wh);
  int i = blockIdx.x * 256 + threadIdx.x;   // 0..32767
  int lane = i & 63;
  int kt   = (i >> 6) & 15;
  int rt   = i >> 10;                       // 0..31
  int row  = rt * 16 + (lane & 15);
  int col  = 512 + kt * 32 + (lane >> 4) * 8;
  const float* src = Ws + (size_t)row * 1024 + col;
  float4 a = *(const float4*)src;
  float4 b = *(const float4*)(src + 4);
  uint4 o;
  o.x = pk2h(a.x, a.y); o.y = pk2h(a.z, a.w);
  o.z = pk2h(b.x, b.y); o.w = pk2h(b.z, b.w);
  WF[((size_t)(g * 32 + rt) * 16 + kt) * 64 + lane] = o;
}

// ---------- kernel 2: projection GEMM (f32 in, bf16 MFMA, f16 out) ----------
// P[g][s][b][j] = f16( sum_k x[b,s,k]*W_g[j,k] + bias_g[j] )
__global__ __launch_bounds__(256) void k_proj_gemm(
    const float* __restrict__ x,      // [B*S][512] f32 (rows m = b*512+s)
    const float* __restrict__ Wr, const float* __restrict__ Wz, const float* __restrict__ Wh,
    const float* __restrict__ br, const float* __restrict__ bz, const float* __restrict__ bh,
    u16* __restrict__ P)
{
  const int g  = blockIdx.z;
  const int bm = blockIdx.x * 64;
  const int bn = blockIdx.y * 64;
  const float* Ws = (g == 0) ? Wr : ((g == 1) ? Wz : Wh);
  __shared__ __align__(16) u16 As[64][32];
  __shared__ __align__(16) u16 Bs[64][32];
  const int tid  = threadIdx.x;
  const int lane = tid & 63;
  const int wm   = (tid >> 6) >> 1;
  const int wn   = (tid >> 6) & 1;
  const int srow = tid >> 2;
  const int scol = (tid & 3) * 8;

  f32x4 zero4 = {0.f, 0.f, 0.f, 0.f};
  f32x4 acc[2][2];
  acc[0][0] = zero4; acc[0][1] = zero4; acc[1][0] = zero4; acc[1][1] = zero4;

  for (int k0 = 0; k0 < 512; k0 += 32) {
    __syncthreads();
    {
      const float* xs = x + (size_t)(bm + srow) * 512 + k0 + scol;
      float4 a = *(const float4*)xs, b = *(const float4*)(xs + 4);
      uint4 av; av.x = pkbf2(a.x, a.y); av.y = pkbf2(a.z, a.w);
      av.z = pkbf2(b.x, b.y); av.w = pkbf2(b.z, b.w);
      *(uint4*)(&As[srow][scol]) = av;
      const float* wsrc = Ws + (size_t)(bn + srow) * 1024 + k0 + scol;   // input half k<512
      float4 c = *(const float4*)wsrc, d = *(const float4*)(wsrc + 4);
      uint4 bv; bv.x = pkbf2(c.x, c.y); bv.y = pkbf2(c.z, c.w);
      bv.z = pkbf2(d.x, d.y); bv.w = pkbf2(d.z, d.w);
      *(uint4*)(&Bs[srow][scol]) = bv;
    }
    __syncthreads();
#pragma unroll
    for (int mi = 0; mi < 2; ++mi) {
      bf16x8 a = *(const bf16x8*)(&As[wm * 32 + mi * 16 + (lane & 15)][(lane >> 4) * 8]);
#pragma unroll
      for (int ni = 0; ni < 2; ++ni) {
        bf16x8 b = *(const bf16x8*)(&Bs[wn * 32 + ni * 16 + (lane & 15)][(lane >> 4) * 8]);
        acc[mi][ni] = __builtin_amdgcn_mfma_f32_16x16x32_bf16(a, b, acc[mi][ni], 0, 0, 0);
      }
    }
  }
  const float* bias = (g == 0) ? br : ((g == 1) ? bz : bh);
#pragma unroll
  for (int mi = 0; mi < 2; ++mi)
#pragma unroll
    for (int ni = 0; ni < 2; ++ni) {
      int col  = bn + wn * 32 + ni * 16 + (lane & 15);
      float bv = bias[col];
#pragma unroll
      for (int r = 0; r < 4; ++r) {
        int row = bm + wm * 32 + mi * 16 + (lane >> 4) * 4 + r;
        int bb = row >> 9, ss = row & 511;
        float v = acc[mi][ni][r] + bv;
        P[((size_t)g * 512 + ss) * (64 * 512) + (size_t)bb * 512 + col] =
            __builtin_bit_cast(u16, (_Float16)v);
      }
    }
}

// ---------- cluster spin barrier (4 blocks, agent scope, step-indexed flags) ----------
__device__ inline void cbar(u32* flag) {
  __syncthreads();    // all waves' global stores drained (vmcnt 0) before release
  if (threadIdx.x == 0) {
    __hip_atomic_fetch_add(flag, 1u, __ATOMIC_ACQ_REL, __HIP_MEMORY_SCOPE_AGENT);
    while (__hip_atomic_load(flag, __ATOMIC_ACQUIRE, __HIP_MEMORY_SCOPE_AGENT) < 4u) {
      __builtin_amdgcn_s_sleep(2);
    }
  }
  __syncthreads();
}

// ---------- kernel 3: GRU scan — W stationary, MFMA recurrence ----------
// 16 blocks x 512 thr. cluster c = blockIdx>>2 owns batches 16c..16c+15;
// sub-block q = blockIdx&3 owns rows [128q,128q+128) of all 3 gates.
// W_r,W_z fragments live in VGPRs (128), W_h fragments in LDS (128KB).
// h kept in C-layout registers; h/rh exchanged via LLC + spin barrier.
__global__ __launch_bounds__(512, 2) void k_gru_scan(
    const float* __restrict__ h0,
    const u16*  __restrict__ P,       // [3][512 ts][64 b][512 j] f16
    const uint4* __restrict__ WF,     // fragment-packed recurrent W (f16)
    u16* __restrict__ HX,             // [4][16][512] f16
    u16* __restrict__ RHX,            // [4][16][512] f16
    u32* __restrict__ flags,          // [512][2][4]
    float* __restrict__ y,
    float* __restrict__ hlast)
{
  const int q = blockIdx.x & 3;
  const int c = blockIdx.x >> 2;
  const int t = threadIdx.x;
  const int w = t >> 6;
  const int l = t & 63;

  __shared__ __align__(16) u16 whlds[8 * 16 * 64 * 8];  // 128 KB: [w][kt][lane][8]
  __shared__ __align__(16) u16 hbuf[16 * 520];          // 16.6 KB, padded rows

  // --- load W fragments ---
  const int rt = q * 8 + w;
  f16x8 wr[16], wz[16];
#pragma unroll
  for (int kt = 0; kt < 16; ++kt) {
    wr[kt] = __builtin_bit_cast(f16x8, WF[((size_t)(0 * 32 + rt) * 16 + kt) * 64 + l]);
    wz[kt] = __builtin_bit_cast(f16x8, WF[((size_t)(1 * 32 + rt) * 16 + kt) * 64 + l]);
    uint4 whv = WF[((size_t)(2 * 32 + rt) * 16 + kt) * 64 + l];
    *(uint4*)&whlds[((w * 16 + kt) * 64 + l) * 8] = whv;
  }

  // --- init h: registers (C-layout) + hbuf (f16 [16][520]) ---
  const int bloc  = l & 15;
  const int bglob = c * 16 + bloc;
  const int j0    = q * 128 + w * 16 + (l >> 4) * 4;
  f32x4 hreg = *(const f32x4*)(h0 + (size_t)bglob * 512 + j0);
  {
    int b = t >> 5, j = (t & 31) * 16;
    const float4* s = (const float4*)(h0 + (size_t)(c * 16 + b) * 512 + j);
    float4 v0 = s[0], v1 = s[1], v2 = s[2], v3 = s[3];
    uint4 o0, o1;
    o0.x = pk2h(v0.x, v0.y); o0.y = pk2h(v0.z, v0.w);
    o0.z = pk2h(v1.x, v1.y); o0.w = pk2h(v1.z, v1.w);
    o1.x = pk2h(v2.x, v2.y); o1.y = pk2h(v2.z, v2.w);
    o1.z = pk2h(v3.x, v3.y); o1.w = pk2h(v3.z, v3.w);
    uint4* d = (uint4*)&hbuf[b * 520 + j];
    d[0] = o0; d[1] = o1;
  }
  __syncthreads();

  u16* HXc  = HX  + (size_t)c * (16 * 512);
  u16* RHXc = RHX + (size_t)c * (16 * 512);
  const int hbase = bloc * 520 + (l >> 4) * 8;

  size_t offp = (size_t)bglob * 512 + j0;        // P step offset (+= 32768/step)
  size_t offy = (size_t)bglob * 262144 + j0;     // y offset (+= 512/step)

  for (int ts = 0; ts < S_; ++ts) {
    // ---- phase A: r,z = sigmoid(W_rz · h + P_rz) ----
    f32x4 ar = {0.f, 0.f, 0.f, 0.f}, az = {0.f, 0.f, 0.f, 0.f};
#pragma unroll
    for (int kt = 0; kt < 16; ++kt) {
      f16x8 bf = *(const f16x8*)&hbuf[hbase + kt * 32];
      ar = __builtin_amdgcn_mfma_f32_16x16x32_f16(wr[kt], bf, ar, 0, 0, 0);
      az = __builtin_amdgcn_mfma_f32_16x16x32_f16(wz[kt], bf, az, 0, 0, 0);
    }
    uint2 pru = *(const uint2*)(P + offp);
    uint2 pzu = *(const uint2*)(P + PJ_GATE + offp);
    h2_t pr0 = __builtin_bit_cast(h2_t, pru.x), pr1 = __builtin_bit_cast(h2_t, pru.y);
    h2_t pz0 = __builtin_bit_cast(h2_t, pzu.x), pz1 = __builtin_bit_cast(h2_t, pzu.y);
    float rr0 = sigmoidf_(ar[0] + (float)pr0[0]);
    float rr1 = sigmoidf_(ar[1] + (float)pr0[1]);
    float rr2 = sigmoidf_(ar[2] + (float)pr1[0]);
    float rr3 = sigmoidf_(ar[3] + (float)pr1[1]);
    float zz0 = sigmoidf_(az[0] + (float)pz0[0]);
    float zz1 = sigmoidf_(az[1] + (float)pz0[1]);
    float zz2 = sigmoidf_(az[2] + (float)pz1[0]);
    float zz3 = sigmoidf_(az[3] + (float)pz1[1]);
    uint2 rh;
    rh.x = pk2h(rr0 * hreg[0], rr1 * hreg[1]);
    rh.y = pk2h(rr2 * hreg[2], rr3 * hreg[3]);
    *(uint2*)&RHXc[bloc * 512 + j0] = rh;

    cbar(&flags[(ts * 2 + 0) * 4 + c]);

    // copy RHX -> hbuf
    {
      int b = t >> 5, j = (t & 31) * 16;
      const uint4* s = (const uint4*)&RHXc[b * 512 + j];
      uint4 v0 = s[0], v1 = s[1];
      uint4* d = (uint4*)&hbuf[b * 520 + j];
      d[0] = v0; d[1] = v1;
    }
    __syncthreads();

    // ---- phase B: htilde = tanh(W_h · rh + P_h); h = z*htilde + (1-z)*h ----
    f32x4 ah = {0.f, 0.f, 0.f, 0.f};
#pragma unroll
    for (int kt = 0; kt < 16; ++kt) {
      f16x8 bf = *(const f16x8*)&hbuf[hbase + kt * 32];
      f16x8 wh = *(const f16x8*)&whlds[((w * 16 + kt) * 64 + l) * 8];
      ah = __builtin_amdgcn_mfma_f32_16x16x32_f16(wh, bf, ah, 0, 0, 0);
    }
    uint2 phu = *(const uint2*)(P + 2 * PJ_GATE + offp);
    h2_t ph0 = __builtin_bit_cast(h2_t, phu.x), ph1 = __builtin_bit_cast(h2_t, phu.y);
    float ht0 = tanhf_(ah[0] + (float)ph0[0]);
    float ht1 = tanhf_(ah[1] + (float)ph0[1]);
    float ht2 = tanhf_(ah[2] + (float)ph1[0]);
    float ht3 = tanhf_(ah[3] + (float)ph1[1]);
    hreg[0] = zz0 * ht0 + (1.f - zz0) * hreg[0];
    hreg[1] = zz1 * ht1 + (1.f - zz1) * hreg[1];
    hreg[2] = zz2 * ht2 + (1.f - zz2) * hreg[2];
    hreg[3] = zz3 * ht3 + (1.f - zz3) * hreg[3];
    *(f32x4*)(y + offy) = hreg;
    uint2 hx;
    hx.x = pk2h(hreg[0], hreg[1]);
    hx.y = pk2h(hreg[2], hreg[3]);
    *(uint2*)&HXc[bloc * 512 + j0] = hx;

    cbar(&flags[(ts * 2 + 1) * 4 + c]);

    // copy HX -> hbuf (next step's h), skip after final step
    if (ts != S_ - 1) {
      int b = t >> 5, j = (t & 31) * 16;
      const uint4* s = (const uint4*)&HXc[b * 512 + j];
      uint4 v0 = s[0], v1 = s[1];
      uint4* d = (uint4*)&hbuf[b * 520 + j];
      d[0] = v0; d[1] = v1;
      __syncthreads();
    }
    offp += 32768;
    offy += 512;
  }

  *(f32x4*)(hlast + (size_t)bglob * 512 + j0) = hreg;
}

// ---------- host ----------
extern "C" void kernel_launch(void* const* d_in, const int* in_sizes, int n_in,
                              void* d_out, int out_size, void* d_ws, size_t ws_size,
                              hipStream_t stream) {
  const float* x  = (const float*)d_in[0];
  const float* h0 = (const float*)d_in[1];
  const float* Wr = (const float*)d_in[2];
  const float* br = (const float*)d_in[3];
  const float* Wz = (const float*)d_in[4];
  const float* bz = (const float*)d_in[5];
  const float* Wh = (const float*)d_in[6];
  const float* bh = (const float*)d_in[7];

  char* ws = (char*)d_ws;
  // layout: WF 1.5MB @0 | P 96MB @2MB | HX 64KB | RHX 64KB | flags 16KB  (~103MB)
  uint4* WF    = (uint4*)ws;
  u16*   P     = (u16*)(ws + 2097152);
  u16*   HX    = (u16*)(ws + 102760448);
  u16*   RHX   = (u16*)(ws + 102825984);
  u32*   flags = (u32*)(ws + 102891520);

  float* y     = (float*)d_out;
  float* hlast = y + (size_t)B_ * S_ * H_;

  hipMemsetAsync(flags, 0, 512 * 2 * 4 * sizeof(u32), stream);
  k_convert_w<<<dim3(128, 3), dim3(256), 0, stream>>>(Wr, Wz, Wh, WF);
  k_proj_gemm<<<dim3(512, 8, 3), dim3(256), 0, stream>>>(x, Wr, Wz, Wh, br, bz, bh, P);
  k_gru_scan<<<dim3(16), dim3(512), 0, stream>>>(h0, P, WF, HX, RHX, flags, y, hlast);
}